// Round 8
// baseline (7549.994 us; speedup 1.0000x reference)
//
#include <hip/hip_runtime.h>

#define Tn 512
#define Hn 512
#define HS 65536           // u32 elements per h ring slot (128*512)
#define NBLK 256

typedef __attribute__((ext_vector_type(8))) short s8v;     // 8 bf16 (MFMA A/B frag)
typedef __attribute__((ext_vector_type(4))) float f4v;     // MFMA acc
typedef __attribute__((ext_vector_type(4))) unsigned u4v;

__device__ __forceinline__ unsigned short f2bf(float f) {  // RNE
  unsigned u = __float_as_uint(f);
  u = u + 0x7fffu + ((u >> 16) & 1u);
  return (unsigned short)(u >> 16);
}
__device__ __forceinline__ float bf2f(unsigned short s) {
  return __uint_as_float(((unsigned)s) << 16);
}
__device__ __forceinline__ float sigm(float v) { return 1.f / (1.f + __expf(-v)); }
__device__ __forceinline__ float tanh_f(float v) {
  v = fminf(fmaxf(v, -15.f), 15.f);
  float e = __expf(2.f * v);
  return (e - 1.f) / (e + 1.f);
}
__device__ __forceinline__ f4v mfma3(s8v ah, s8v al, s8v wh, s8v wl, f4v c) {
  c = __builtin_amdgcn_mfma_f32_16x16x32_bf16(ah, wh, c, 0, 0, 0);
  c = __builtin_amdgcn_mfma_f32_16x16x32_bf16(al, wh, c, 0, 0, 0);
  c = __builtin_amdgcn_mfma_f32_16x16x32_bf16(ah, wl, c, 0, 0, 0);
  return c;
}

// MALL-coherent (agent-scope, relaxed) accessors -> sc1 ops, no cache maintenance.
__device__ __forceinline__ unsigned long long ld_mall64(const unsigned long long* p) {
  return __hip_atomic_load(p, __ATOMIC_RELAXED, __HIP_MEMORY_SCOPE_AGENT);
}
__device__ __forceinline__ void st_mall(unsigned* p, unsigned v) {
  __hip_atomic_store(p, v, __ATOMIC_RELAXED, __HIP_MEMORY_SCOPE_AGENT);
}

// Dual-line flag poll: lanes 0..31 check lineA[lane] >= ta, lanes 32..63 check
// lineB[lane-32] >= tb. One vector load polls both conditions.
__device__ __forceinline__ void poll2(const int* pa, int ta, const int* pb2, int tb,
                                      int lane) {
  const int* p = (lane < 32) ? (pa + lane) : (pb2 + (lane - 32));
  const int tgt = (lane < 32) ? ta : tb;
  for (;;) {
    int v = (int)__hip_atomic_load(p, __ATOMIC_RELAXED, __HIP_MEMORY_SCOPE_AGENT);
    if (__all(v >= tgt)) break;
    __builtin_amdgcn_s_sleep(1);
  }
  asm volatile("" ::: "memory");   // no data loads hoisted above the poll
}

// ---------------- persistent fused 2-layer GRU, 8-wave blocks ----------------
// 256 blocks x 512 threads. g = bid&7 = mq*2+layer; jg = bid>>3 (16 cols).
// Group (layer,mq) = 32 jg-blocks exchanging h via sc1 rings + per-block flags
// (flags[g][jg] = completed steps); in-wave vmcnt(0) release before flag store.
// 8 waves: wv<4 input-side (x for l0, h1[t] for l1), wv>=4 h-side; each wave
// owns K-quarter kq = wv&3 (96 weight VGPRs, 24 MFMA frags hi+lo).
// Wave 4 combines 7 LDS partial slots + own acc, does gates, publishes h+flag.
// One __syncthreads per step ('part' double-buffered by parity).
__global__ __launch_bounds__(512, 1) void gru_fused(
    const float* __restrict__ x,
    const float* __restrict__ Wih0, const float* __restrict__ Whh0,
    const float* __restrict__ bih0, const float* __restrict__ bhh0,
    const float* __restrict__ Wih1, const float* __restrict__ Whh1,
    const float* __restrict__ bih1, const float* __restrict__ bhh1,
    int* __restrict__ flags,       // [8][32] int
    unsigned* __restrict__ h1ring, // 4 slots x 65536 u32
    unsigned* __restrict__ h2ring, // 2 slots x 65536 u32
    float* __restrict__ h2fin) {
  __shared__ float part[2][7][64][25];   // [parity][slot][lane][elem] = 89.6 KB

  const int tid = threadIdx.x, lane = tid & 63, wv = tid >> 6;
  const bool inside = (wv < 4);          // input-side wave
  const int kq = wv & 3;                 // K quarter (128 k)
  const bool comb = (wv == 4);           // combiner/epilogue wave
  const int colr = lane & 15, kg = lane >> 4;

  const int bid = blockIdx.x;
  const int g = bid & 7;
  const int layer = g & 1;
  const int mq = g >> 1;                 // row quarter (32 rows)
  const int jg = bid >> 3;               // 0..31 column group
  const int col = jg * 16 + colr;

  // ---- load weight fragments (this wave's matrix + K-quarter) ----
  // B-frag: lane holds W[col][k = kq*128 + ks*32 + kg*8 + e], ks = 0..3
  const float* W = (layer == 0) ? (inside ? Wih0 : Whh0) : (inside ? Wih1 : Whh1);
  s8v wh[3][4], wl[3][4];
#pragma unroll
  for (int gg = 0; gg < 3; ++gg) {
    const float* wrow = W + (size_t)(gg * Hn + col) * Hn + kq * 128 + kg * 8;
#pragma unroll
    for (int ks = 0; ks < 4; ++ks) {
#pragma unroll
      for (int e = 0; e < 8; ++e) {
        float v = wrow[ks * 32 + e];
        unsigned short hi = f2bf(v);
        wh[gg][ks][e] = (short)hi;
        wl[gg][ks][e] = (short)f2bf(v - bf2f(hi));
      }
    }
  }

  // biases: only the combiner wave
  float brz = 0, bzz = 0, bin = 0, bhn = 0;
  if (comb) {
    const float* bi = layer ? bih1 : bih0;
    const float* bb = layer ? bhh1 : bhh0;
    brz = bi[col] + bb[col];
    bzz = bi[Hn + col] + bb[Hn + col];
    bin = bi[2 * Hn + col];
    bhn = bb[2 * Hn + col];
  }

  const bool is_xw = (layer == 0 && inside);   // x-prefetching wave

  float4 xp[2][4][2];   // 2 mt x 4 ks x 2 float4 (K-quarter of x row)
  if (is_xw) {
#pragma unroll
    for (int mt = 0; mt < 2; ++mt) {
      const int rowA = mq * 32 + mt * 16 + colr;
      const float* xq = x + ((size_t)rowA * Tn) * 512 + kq * 128 + kg * 8;  // t = 0
#pragma unroll
      for (int ks = 0; ks < 4; ++ks) {
        xp[mt][ks][0] = *(const float4*)(xq + ks * 32);
        xp[mt][ks][1] = *(const float4*)(xq + ks * 32 + 4);
      }
    }
  }

  int* const ownline = flags + g * 32;
  int* const l0line = flags + (mq * 2) * 32;
  int* const l1line = flags + (mq * 2 + 1) * 32;

  float hown[2][4] = {{0.f, 0.f, 0.f, 0.f}, {0.f, 0.f, 0.f, 0.f}};

#pragma unroll 1
  for (int t = 0; t < Tn; ++t) {
    const int pb = t & 1;

    // ---- ordering polls (flags ARE the barrier) ----
    if (layer == 0) {
      if (!inside) {
        if (comb) poll2(ownline, t, l1line, t - 3, lane);  // h1[t-1] ready + ring free
        else      poll2(ownline, t, ownline, t, lane);
      }
    } else {
      if (inside) poll2(l0line, t + 1, l0line, t + 1, lane);  // h1[t] ready
      else        poll2(ownline, t, ownline, t, lane);        // h2[t-1] ready
    }

    f4v acc[2][3];
#pragma unroll
    for (int mt = 0; mt < 2; ++mt)
#pragma unroll
      for (int gg = 0; gg < 3; ++gg) acc[mt][gg] = (f4v){0.f, 0.f, 0.f, 0.f};

    if (is_xw) {
      // ---- x-input GEMM from prefetched registers; hi/lo by truncation ----
#pragma unroll
      for (int mt = 0; mt < 2; ++mt) {
#pragma unroll
        for (int ks = 0; ks < 4; ++ks) {
          float v[8];
          v[0] = xp[mt][ks][0].x; v[1] = xp[mt][ks][0].y;
          v[2] = xp[mt][ks][0].z; v[3] = xp[mt][ks][0].w;
          v[4] = xp[mt][ks][1].x; v[5] = xp[mt][ks][1].y;
          v[6] = xp[mt][ks][1].z; v[7] = xp[mt][ks][1].w;
          u4v au, lu;
#pragma unroll
          for (int q = 0; q < 4; ++q) {
            unsigned u0 = __float_as_uint(v[2 * q]);
            unsigned u1 = __float_as_uint(v[2 * q + 1]);
            unsigned m0 = u0 & 0xffff0000u, m1 = u1 & 0xffff0000u;
            au[q] = (u0 >> 16) | m1;
            float l0 = v[2 * q] - __uint_as_float(m0);
            float l1 = v[2 * q + 1] - __uint_as_float(m1);
            lu[q] = (__float_as_uint(l0) >> 16) | (__float_as_uint(l1) & 0xffff0000u);
          }
          s8v ah = __builtin_bit_cast(s8v, au);
          s8v al = __builtin_bit_cast(s8v, lu);
#pragma unroll
          for (int gg = 0; gg < 3; ++gg)
            acc[mt][gg] = mfma3(ah, al, wh[gg][ks], wl[gg][ks], acc[mt][gg]);
        }
      }
      // issue next-step x loads (overlap everything downstream)
      const int tpre = (t + 1 < Tn) ? (t + 1) : (Tn - 1);
#pragma unroll
      for (int mt = 0; mt < 2; ++mt) {
        const int rowA = mq * 32 + mt * 16 + colr;
        const float* xq = x + ((size_t)rowA * Tn + tpre) * 512 + kq * 128 + kg * 8;
#pragma unroll
        for (int ks = 0; ks < 4; ++ks) {
          xp[mt][ks][0] = *(const float4*)(xq + ks * 32);
          xp[mt][ks][1] = *(const float4*)(xq + ks * 32 + 4);
        }
      }
    } else {
      // ---- h GEMM: full-batch 64-bit sc1 loads (32 regs x 2 mt), then MFMA ----
      const unsigned* src;
      if (layer == 0)  src = h1ring + (size_t)((t - 1) & 3) * HS;  // h1[t-1]
      else if (inside) src = h1ring + (size_t)(t & 3) * HS;        // h1[t]
      else             src = h2ring + (size_t)((t - 1) & 1) * HS;  // h2[t-1]

      unsigned long long ub[2][16];
#pragma unroll
      for (int mt = 0; mt < 2; ++mt) {
        const int rowA = mq * 32 + mt * 16 + colr;
        const unsigned long long* pb64 = (const unsigned long long*)
            (src + (size_t)rowA * 512 + kq * 128 + kg * 8);
#pragma unroll
        for (int i = 0; i < 16; ++i) ub[mt][i] = ld_mall64(pb64 + (i >> 2) * 16 + (i & 3));
      }
#pragma unroll
      for (int mt = 0; mt < 2; ++mt) {
#pragma unroll
        for (int ks = 0; ks < 4; ++ks) {
          u4v ahw, alw;
#pragma unroll
          for (int j = 0; j < 4; ++j) {
            unsigned a = (unsigned)ub[mt][ks * 4 + j];
            unsigned b = (unsigned)(ub[mt][ks * 4 + j] >> 32);
            ahw[j] = (a >> 16) | (b & 0xffff0000u);
            alw[j] = (a & 0xffffu) | (b << 16);
          }
          s8v AH = __builtin_bit_cast(s8v, ahw);
          s8v AL = __builtin_bit_cast(s8v, alw);
#pragma unroll
          for (int gg = 0; gg < 3; ++gg)
            acc[mt][gg] = mfma3(AH, AL, wh[gg][ks], wl[gg][ks], acc[mt][gg]);
        }
      }
    }

    // partial handoff: slots 0..3 = input-side kq, 4..6 = h-side kq 1..3
    if (!comb) {
      const int slot = inside ? kq : (3 + kq);   // wv5,6,7 -> 4,5,6
#pragma unroll
      for (int mt = 0; mt < 2; ++mt)
#pragma unroll
        for (int gg = 0; gg < 3; ++gg)
#pragma unroll
          for (int r = 0; r < 4; ++r)
            part[pb][slot][lane][mt * 12 + gg * 4 + r] = acc[mt][gg][r];
    }
    __syncthreads();   // the ONLY barrier per step

    // ---- combiner: sum partials, gates, publish h + flag ----
    if (comb) {
      unsigned* od = layer ? (h2ring + (size_t)(t & 1) * HS)
                           : (h1ring + (size_t)(t & 3) * HS);
#pragma unroll
      for (int mt = 0; mt < 2; ++mt) {
#pragma unroll
        for (int r = 0; r < 4; ++r) {
          const int i0 = mt * 12 + r;
          float xr = part[pb][0][lane][i0] + part[pb][1][lane][i0]
                   + part[pb][2][lane][i0] + part[pb][3][lane][i0];
          float xz = part[pb][0][lane][i0 + 4] + part[pb][1][lane][i0 + 4]
                   + part[pb][2][lane][i0 + 4] + part[pb][3][lane][i0 + 4];
          float xn = part[pb][0][lane][i0 + 8] + part[pb][1][lane][i0 + 8]
                   + part[pb][2][lane][i0 + 8] + part[pb][3][lane][i0 + 8];
          float hr = acc[mt][0][r] + part[pb][4][lane][i0]
                   + part[pb][5][lane][i0] + part[pb][6][lane][i0];
          float hz = acc[mt][1][r] + part[pb][4][lane][i0 + 4]
                   + part[pb][5][lane][i0 + 4] + part[pb][6][lane][i0 + 4];
          float hn = acc[mt][2][r] + part[pb][4][lane][i0 + 8]
                   + part[pb][5][lane][i0 + 8] + part[pb][6][lane][i0 + 8];
          float rr = sigm(xr + hr + brz);
          float zz = sigm(xz + hz + bzz);
          float nn = tanh_f(xn + bin + rr * (hn + bhn));
          float h = (1.f - zz) * nn + zz * hown[mt][r];
          hown[mt][r] = h;
          const int row = mq * 32 + mt * 16 + kg * 4 + r;
          unsigned short hi = f2bf(h);
          unsigned pk = ((unsigned)hi << 16) | (unsigned)f2bf(h - bf2f(hi));
          st_mall(od + (size_t)row * 512 + col, pk);
          if (layer == 1 && t == Tn - 1) h2fin[(size_t)row * 512 + col] = h;
        }
      }
      // release: drain h stores (this wave only), then publish flag
      asm volatile("s_waitcnt vmcnt(0)" ::: "memory");
      if (lane == 0)
        st_mall((unsigned*)(ownline + jg), (unsigned)(t + 1));
    }
  }
}

// ---------- epilogue: out = h2_last @ Wfc^T + bfc ----------
__global__ __launch_bounds__(256) void fc_kernel(const float* __restrict__ h2,
                                                 const float* __restrict__ Wfc,
                                                 const float* __restrict__ bfc,
                                                 float* __restrict__ out) {
  int gid = blockIdx.x * 256 + threadIdx.x;  // 0..16383
  int b = gid >> 7, o = gid & 127;
  const float* hp = h2 + (size_t)b * Hn;
  const float* wp = Wfc + (size_t)o * Hn;
  float acc = bfc[o];
#pragma unroll 8
  for (int k = 0; k < Hn; k += 4) {
    float4 h = *(const float4*)(hp + k);
    float4 w = *(const float4*)(wp + k);
    acc = fmaf(h.x, w.x, acc); acc = fmaf(h.y, w.y, acc);
    acc = fmaf(h.z, w.z, acc); acc = fmaf(h.w, w.w, acc);
  }
  out[gid] = acc;
}

// ---------- epilogue: out_cate = out @ Wfcc^T + bfcc ----------
__global__ __launch_bounds__(256) void fcc_kernel(const float* __restrict__ outv,
                                                  const float* __restrict__ Wfcc,
                                                  const float* __restrict__ bfcc,
                                                  float* __restrict__ oc) {
  int gid = blockIdx.x * 256 + threadIdx.x;  // 0..49151
  int b = gid / 384, g = gid - b * 384;
  const float* op = outv + (size_t)b * 128;
  const float* wp = Wfcc + (size_t)g * 128;
  float acc = bfcc[g];
#pragma unroll 8
  for (int k = 0; k < 128; k += 4) {
    float4 o4 = *(const float4*)(op + k);
    float4 w4 = *(const float4*)(wp + k);
    acc = fmaf(o4.x, w4.x, acc); acc = fmaf(o4.y, w4.y, acc);
    acc = fmaf(o4.z, w4.z, acc); acc = fmaf(o4.w, w4.w, acc);
  }
  oc[gid] = acc;
}

extern "C" void kernel_launch(void* const* d_in, const int* in_sizes, int n_in,
                              void* d_out, int out_size, void* d_ws, size_t ws_size,
                              hipStream_t stream) {
  (void)in_sizes; (void)n_in; (void)out_size; (void)ws_size;
  const float* x    = (const float*)d_in[0];
  const float* Wih0 = (const float*)d_in[1];
  const float* Whh0 = (const float*)d_in[2];
  const float* bih0 = (const float*)d_in[3];
  const float* bhh0 = (const float*)d_in[4];
  const float* Wih1 = (const float*)d_in[5];
  const float* Whh1 = (const float*)d_in[6];
  const float* bih1 = (const float*)d_in[7];
  const float* bhh1 = (const float*)d_in[8];
  const float* Wfc  = (const float*)d_in[9];
  const float* bfc  = (const float*)d_in[10];
  const float* Wfcc = (const float*)d_in[11];
  const float* bfcc = (const float*)d_in[12];

  char* w = (char*)d_ws;
  int* flags = (int*)w;                            // [8][32] int, 1 KB
  unsigned* h1ring = (unsigned*)(w + 8192);        // 4 * 65536 u32 = 1 MB
  unsigned* h2ring = h1ring + 4 * HS;              // 2 * 65536 u32 = 512 KB
  float* h2fin = (float*)(h2ring + 2 * HS);        // 256 KB
  const size_t total = 8192 + (size_t)4 * HS * 4 + (size_t)2 * HS * 4 + (size_t)HS * 4;

  hipMemsetAsync(d_ws, 0, total, stream);

  gru_fused<<<NBLK, 512, 0, stream>>>(x, Wih0, Whh0, bih0, bhh0,
                                      Wih1, Whh1, bih1, bhh1,
                                      flags, h1ring, h2ring, h2fin);

  float* out = (float*)d_out;
  fc_kernel<<<64, 256, 0, stream>>>(h2fin, Wfc, bfc, out);
  fcc_kernel<<<192, 256, 0, stream>>>(out, Wfcc, bfcc, out + 16384);
}